// Round 1
// baseline (1290.008 us; speedup 1.0000x reference)
//
#include <hip/hip_runtime.h>

typedef unsigned short ushort_t;
typedef unsigned int u32;
typedef __attribute__((ext_vector_type(8))) short bf16x8;
typedef __attribute__((ext_vector_type(4))) float f32x4;

#define B_ 4
#define S_ 2048
#define D_ 2048
#define H_ 16
#define HD_ 128

__device__ __forceinline__ ushort_t f2bf(float f) {
  u32 x = __builtin_bit_cast(u32, f);
  x += 0x7fffu + ((x >> 16) & 1u);
  return (ushort_t)(x >> 16);
}
__device__ __forceinline__ float bf2f(ushort_t u) {
  u32 x = ((u32)u) << 16;
  return __builtin_bit_cast(float, x);
}

// ---------------- elementwise f32 -> bf16 convert ----------------
struct __align__(8) us4 { ushort_t x, y, z, w; };

__global__ void k_cvt_bf16(const float* __restrict__ in, ushort_t* __restrict__ out, int n) {
  int i = (blockIdx.x * 256 + threadIdx.x) * 4;
  if (i >= n) return;
  float4 v = *(const float4*)(in + i);
  us4 o;
  o.x = f2bf(v.x); o.y = f2bf(v.y); o.z = f2bf(v.z); o.w = f2bf(v.w);
  *(us4*)(out + i) = o;
}

// ---------------- f32 [R][C] -> bf16 [C][R] transpose ----------------
__global__ void k_transpose_bf16(const float* __restrict__ in, ushort_t* __restrict__ out,
                                 int R, int C) {
  __shared__ float ld[32][33];
  int c0 = blockIdx.x * 32, r0 = blockIdx.y * 32;
  int tc = threadIdx.x & 31, tr = threadIdx.x >> 5;  // tr 0..7
#pragma unroll
  for (int i = 0; i < 4; ++i) {
    int r = tr + i * 8;
    ld[r][tc] = in[(size_t)(r0 + r) * C + c0 + tc];
  }
  __syncthreads();
#pragma unroll
  for (int i = 0; i < 4; ++i) {
    int r = tr + i * 8;
    out[(size_t)(c0 + r) * R + r0 + tc] = f2bf(ld[tc][r]);
  }
}

// ---------------- RoPE cos/sin tables: [S][64] each ----------------
__global__ void k_rope_tables(float* __restrict__ cost, float* __restrict__ sint) {
  int i = blockIdx.x * 256 + threadIdx.x;  // < S_*64
  int s = i >> 6, j = i & 63;
  double th = pow(10000.0, -(double)j / 64.0);
  double a = (double)s * th;
  cost[i] = (float)cos(a);
  sint[i] = (float)sin(a);
}

// ---------------- bf16 GEMM: C[M][N] = A[M][K] * Bt[N][K]^T (+bias) ----------------
// 128x128 tile, BK=32, 4 waves (2x2 of 64x64), global_load_lds staging.
template <int FINAL>
__global__ __launch_bounds__(256, 2) void k_gemm_bt(const ushort_t* __restrict__ A,
                                                    const ushort_t* __restrict__ Bt,
                                                    void* __restrict__ Cout,
                                                    const float* __restrict__ bias,
                                                    int M, int N, int K) {
  __shared__ __attribute__((aligned(16))) ushort_t As[128 * 32];
  __shared__ __attribute__((aligned(16))) ushort_t Bs[128 * 32];
  const int tid = threadIdx.x;
  const int w = tid >> 6, l = tid & 63;
  const int lr = l & 15, lg = l >> 4;
  const int m0 = blockIdx.y * 128, n0 = blockIdx.x * 128;
  const int wr = (w >> 1) * 64, wc = (w & 1) * 64;
  f32x4 acc[4][4] = {};
  for (int kt = 0; kt < K; kt += 32) {
#pragma unroll
    for (int i = 0; i < 2; ++i) {
      int c = i * 256 + w * 64 + l;  // 16B chunk id; row=c>>2, sub=c&3
      const ushort_t* ga = A + (size_t)(m0 + (c >> 2)) * K + kt + (c & 3) * 8;
      const ushort_t* gb = Bt + (size_t)(n0 + (c >> 2)) * K + kt + (c & 3) * 8;
      __builtin_amdgcn_global_load_lds(
          (const __attribute__((address_space(1))) u32*)ga,
          (__attribute__((address_space(3))) u32*)(As + (size_t)(i * 256 + w * 64) * 8), 16, 0, 0);
      __builtin_amdgcn_global_load_lds(
          (const __attribute__((address_space(1))) u32*)gb,
          (__attribute__((address_space(3))) u32*)(Bs + (size_t)(i * 256 + w * 64) * 8), 16, 0, 0);
    }
    __syncthreads();
    bf16x8 af[4], bfr[4];
#pragma unroll
    for (int m = 0; m < 4; ++m)
      af[m] = *(const bf16x8*)(As + (wr + m * 16 + lr) * 32 + lg * 8);
#pragma unroll
    for (int n = 0; n < 4; ++n)
      bfr[n] = *(const bf16x8*)(Bs + (wc + n * 16 + lr) * 32 + lg * 8);
#pragma unroll
    for (int m = 0; m < 4; ++m)
#pragma unroll
      for (int n = 0; n < 4; ++n)
        acc[m][n] = __builtin_amdgcn_mfma_f32_16x16x32_bf16(af[m], bfr[n], acc[m][n], 0, 0, 0);
    __syncthreads();
  }
#pragma unroll
  for (int m = 0; m < 4; ++m) {
#pragma unroll
    for (int n = 0; n < 4; ++n) {
#pragma unroll
      for (int j = 0; j < 4; ++j) {
        int row = m0 + wr + m * 16 + lg * 4 + j;
        int col = n0 + wc + n * 16 + lr;
        if (FINAL) {
          ((float*)Cout)[(size_t)row * N + col] = acc[m][n][j] + bias[col];
        } else {
          ((ushort_t*)Cout)[(size_t)row * N + col] = f2bf(acc[m][n][j]);
        }
      }
    }
  }
}

// ---------------- split QKV slice; RoPE for Q/K; transpose for V ----------------
// tmp: [B*S][D] bf16 (one 2048-wide slice of qkv). mode 0: Q rope -> [B*H][S][HD]
// mode 1: K rope -> [B*H][S][HD]; mode 2: V -> [B*H][HD][S]
__global__ void k_split_rope(const ushort_t* __restrict__ tmp, ushort_t* __restrict__ dst,
                             const float* __restrict__ cost, const float* __restrict__ sint,
                             int mode) {
  int s0 = blockIdx.x * 32;
  int h = blockIdx.y;
  int b = blockIdx.z;
  int bh = b * H_ + h;
  if (mode < 2) {
#pragma unroll
    for (int i = 0; i < 16; ++i) {
      int e = i * 256 + threadIdx.x;
      int sr = e >> 7, d = e & 127;
      int s = s0 + sr;
      size_t base = (size_t)(b * S_ + s) * D_ + h * HD_;
      float v = bf2f(tmp[base + d]);
      int j = d & 63;
      float cth = cost[s * 64 + j], sth = sint[s * 64 + j];
      int pd = (d < 64) ? d + 64 : d - 64;
      float v2 = bf2f(tmp[base + pd]);
      float r = (d < 64) ? v * cth - v2 * sth : v * cth + v2 * sth;
      dst[((size_t)bh * S_ + s) * HD_ + d] = f2bf(r);
    }
  } else {
    __shared__ ushort_t ld[32][132];
#pragma unroll
    for (int i = 0; i < 16; ++i) {
      int e = i * 256 + threadIdx.x;
      int sr = e >> 7, d = e & 127;
      ld[sr][d] = tmp[(size_t)(b * S_ + s0 + sr) * D_ + h * HD_ + d];
    }
    __syncthreads();
#pragma unroll
    for (int i = 0; i < 16; ++i) {
      int e = i * 256 + threadIdx.x;
      int d = e >> 5, sr = e & 31;
      dst[((size_t)bh * HD_ + d) * S_ + s0 + sr] = ld[sr][d];
    }
  }
}

// ---------------- causal flash attention ----------------
// Q,K: [B*H][S][HD] bf16 (RoPE'd); Vt: [B*H][HD][S] bf16; O: [B][S][H*HD] bf16
// block = 4 waves; wave w owns 16 q rows; 64 keys per iteration.
// Swapped QK^T: mfma(K_frag, Q_frag) -> lane holds scores for q = lane&15.
__global__ __launch_bounds__(256, 2) void k_attn(const ushort_t* __restrict__ Q,
                                                 const ushort_t* __restrict__ K,
                                                 const ushort_t* __restrict__ Vt,
                                                 ushort_t* __restrict__ O) {
  __shared__ __attribute__((aligned(16))) ushort_t Pl[4][16][72];  // pad 72 to kill bank conflicts
  const int qt = blockIdx.x, bh = blockIdx.y;
  const int b = bh >> 4, h = bh & 15;
  const int tid = threadIdx.x;
  const int w = tid >> 6, l = tid & 63;
  const int lr = l & 15, lg = l >> 4;
  const int qbase = qt * 64 + w * 16;
  const ushort_t* Qp = Q + (size_t)bh * S_ * HD_;
  const ushort_t* Kp = K + (size_t)bh * S_ * HD_;
  const ushort_t* Vp = Vt + (size_t)bh * HD_ * S_;
  const float scale = 0.08838834764831845f;  // 1/sqrt(128)

  bf16x8 qf[4];
#pragma unroll
  for (int dw = 0; dw < 4; ++dw)
    qf[dw] = *(const bf16x8*)(Qp + (size_t)(qbase + lr) * HD_ + dw * 32 + lg * 8);

  float mrun = -1e30f, lrun = 0.f;
  f32x4 oacc[8] = {};
  const int qg = qbase + lr;  // this lane's q row (stats owner)
  const int nkt = qt + 1;
  for (int kt = 0; kt < nkt; ++kt) {
    const int kb = kt * 64;
    f32x4 st[4];
#pragma unroll
    for (int t = 0; t < 4; ++t) {
      f32x4 a = {};
#pragma unroll
      for (int dw = 0; dw < 4; ++dw) {
        bf16x8 kf = *(const bf16x8*)(Kp + (size_t)(kb + t * 16 + lr) * HD_ + dw * 32 + lg * 8);
        a = __builtin_amdgcn_mfma_f32_16x16x32_bf16(kf, qf[dw], a, 0, 0, 0);
      }
      st[t] = a;
    }
    // mask + scale + tile max (scores for q=qg live at k = kb + t*16 + lg*4 + j)
    float tmax = -1e30f;
#pragma unroll
    for (int t = 0; t < 4; ++t) {
#pragma unroll
      for (int j = 0; j < 4; ++j) {
        int kg = kb + t * 16 + lg * 4 + j;
        float s = st[t][j] * scale;
        s = (kg > qg) ? -1e30f : s;
        st[t][j] = s;
        tmax = fmaxf(tmax, s);
      }
    }
    tmax = fmaxf(tmax, __shfl_xor(tmax, 16, 64));
    tmax = fmaxf(tmax, __shfl_xor(tmax, 32, 64));
    float mnew = fmaxf(mrun, tmax);
    float alpha = __expf(mrun - mnew);
    mrun = mnew;
    float psum = 0.f;
#pragma unroll
    for (int t = 0; t < 4; ++t) {
      float p0 = __expf(st[t][0] - mnew);
      float p1 = __expf(st[t][1] - mnew);
      float p2 = __expf(st[t][2] - mnew);
      float p3 = __expf(st[t][3] - mnew);
      psum += (p0 + p1) + (p2 + p3);
      u32 pk0 = (u32)f2bf(p0) | ((u32)f2bf(p1) << 16);
      u32 pk1 = (u32)f2bf(p2) | ((u32)f2bf(p3) << 16);
      *(u32*)&Pl[w][lr][t * 16 + lg * 4] = pk0;
      *(u32*)&Pl[w][lr][t * 16 + lg * 4 + 2] = pk1;
    }
    psum += __shfl_xor(psum, 16, 64);
    psum += __shfl_xor(psum, 32, 64);
    lrun = lrun * alpha + psum;
    // rescale O (lane's O rows are lg*4+j; alpha for row r lives at lane r)
    float a0 = __shfl(alpha, lg * 4 + 0, 64);
    float a1 = __shfl(alpha, lg * 4 + 1, 64);
    float a2 = __shfl(alpha, lg * 4 + 2, 64);
    float a3 = __shfl(alpha, lg * 4 + 3, 64);
#pragma unroll
    for (int dt = 0; dt < 8; ++dt) {
      oacc[dt][0] *= a0;
      oacc[dt][1] *= a1;
      oacc[dt][2] *= a2;
      oacc[dt][3] *= a3;
    }
    // PV: A = P[16q x 32k] from LDS, B = V[32k x 16d] from Vt (contiguous along k)
#pragma unroll
    for (int kw = 0; kw < 2; ++kw) {
      bf16x8 pa = *(const bf16x8*)&Pl[w][lr][kw * 32 + lg * 8];
#pragma unroll
      for (int dt = 0; dt < 8; ++dt) {
        bf16x8 vf = *(const bf16x8*)(Vp + (size_t)(dt * 16 + lr) * S_ + kb + kw * 32 + lg * 8);
        oacc[dt] = __builtin_amdgcn_mfma_f32_16x16x32_bf16(pa, vf, oacc[dt], 0, 0, 0);
      }
    }
  }
  float l0 = __shfl(lrun, lg * 4 + 0, 64);
  float l1 = __shfl(lrun, lg * 4 + 1, 64);
  float l2 = __shfl(lrun, lg * 4 + 2, 64);
  float l3 = __shfl(lrun, lg * 4 + 3, 64);
  float i0 = 1.f / l0, i1 = 1.f / l1, i2 = 1.f / l2, i3 = 1.f / l3;
  ushort_t* Op = O + (size_t)(b * S_ + qbase) * D_ + h * HD_;
#pragma unroll
  for (int dt = 0; dt < 8; ++dt) {
    Op[(size_t)(lg * 4 + 0) * D_ + dt * 16 + lr] = f2bf(oacc[dt][0] * i0);
    Op[(size_t)(lg * 4 + 1) * D_ + dt * 16 + lr] = f2bf(oacc[dt][1] * i1);
    Op[(size_t)(lg * 4 + 2) * D_ + dt * 16 + lr] = f2bf(oacc[dt][2] * i2);
    Op[(size_t)(lg * 4 + 3) * D_ + dt * 16 + lr] = f2bf(oacc[dt][3] * i3);
  }
}

// ---------------- launch ----------------
extern "C" void kernel_launch(void* const* d_in, const int* in_sizes, int n_in,
                              void* d_out, int out_size, void* d_ws, size_t ws_size,
                              hipStream_t stream) {
  const float* x = (const float*)d_in[0];
  const float* Wqkv = (const float*)d_in[1];
  const float* Wout = (const float*)d_in[2];
  const float* bout = (const float*)d_in[3];
  char* ws = (char*)d_ws;

  // workspace layout (bytes); xb region is reused as attention output O.
  ushort_t* xb = (ushort_t*)(ws + 0);                  // [8192][2048] bf16 (33.5MB) -> later O
  ushort_t* Wqt = (ushort_t*)(ws + 33554432ull);       // [6144][2048] bf16 (25.2MB)
  ushort_t* tmp = (ushort_t*)(ws + 58720256ull);       // [8192][2048] bf16 (33.5MB) -> later Wout^T
  ushort_t* Qb = (ushort_t*)(ws + 92274688ull);        // [64][2048][128]
  ushort_t* Kb = (ushort_t*)(ws + 125829120ull);       // [64][2048][128]
  ushort_t* Vb = (ushort_t*)(ws + 159383552ull);       // [64][128][2048]
  float* cost = (float*)(ws + 192937984ull);           // [2048][64]
  float* sint = (float*)(ws + 193462272ull);           // [2048][64]

  const int M = B_ * S_;  // 8192

  k_cvt_bf16<<<dim3((M * D_) / 4 / 256), 256, 0, stream>>>(x, xb, M * D_);
  k_transpose_bf16<<<dim3(3 * D_ / 32, D_ / 32), 256, 0, stream>>>(Wqkv, Wqt, D_, 3 * D_);
  k_rope_tables<<<dim3(S_ * 64 / 256), 256, 0, stream>>>(cost, sint);

  for (int p = 0; p < 3; ++p) {
    k_gemm_bt<0><<<dim3(D_ / 128, M / 128), 256, 0, stream>>>(
        xb, Wqt + (size_t)p * D_ * D_, tmp, nullptr, M, D_, D_);
    ushort_t* dst = (p == 0) ? Qb : (p == 1) ? Kb : Vb;
    k_split_rope<<<dim3(S_ / 32, H_, B_), 256, 0, stream>>>(tmp, dst, cost, sint, p);
  }

  k_attn<<<dim3(S_ / 64, B_ * H_), 256, 0, stream>>>(Qb, Kb, Vb, xb /* reuse as O */);

  // Wout^T into tmp region (tmp is dead now)
  k_transpose_bf16<<<dim3(D_ / 32, D_ / 32), 256, 0, stream>>>(Wout, tmp, D_, D_);
  k_gemm_bt<1><<<dim3(D_ / 128, M / 128), 256, 0, stream>>>(
      xb, tmp, d_out, bout, M, D_, D_);
}

// Round 2
// 590.577 us; speedup vs baseline: 2.1843x; 2.1843x over previous
//
#include <hip/hip_runtime.h>

typedef unsigned short ushort_t;
typedef unsigned int u32;
typedef __attribute__((ext_vector_type(8))) short bf16x8;
typedef __attribute__((ext_vector_type(4))) float f32x4;

#define B_ 4
#define S_ 2048
#define D_ 2048
#define H_ 16
#define HD_ 128

__device__ __forceinline__ ushort_t f2bf(float f) {
  u32 x = __builtin_bit_cast(u32, f);
  x += 0x7fffu + ((x >> 16) & 1u);
  return (ushort_t)(x >> 16);
}
__device__ __forceinline__ float bf2f(ushort_t u) {
  u32 x = ((u32)u) << 16;
  return __builtin_bit_cast(float, x);
}

// ---------------- elementwise f32 -> bf16 convert ----------------
struct __align__(8) us4 { ushort_t x, y, z, w; };

__global__ void k_cvt_bf16(const float* __restrict__ in, ushort_t* __restrict__ out, int n) {
  int i = (blockIdx.x * 256 + threadIdx.x) * 4;
  if (i >= n) return;
  float4 v = *(const float4*)(in + i);
  us4 o;
  o.x = f2bf(v.x); o.y = f2bf(v.y); o.z = f2bf(v.z); o.w = f2bf(v.w);
  *(us4*)(out + i) = o;
}

// ---------------- f32 [R][C] -> bf16 [C][R] transpose ----------------
__global__ void k_transpose_bf16(const float* __restrict__ in, ushort_t* __restrict__ out,
                                 int R, int C) {
  __shared__ float ld[32][33];
  int c0 = blockIdx.x * 32, r0 = blockIdx.y * 32;
  int tc = threadIdx.x & 31, tr = threadIdx.x >> 5;  // tr 0..7
#pragma unroll
  for (int i = 0; i < 4; ++i) {
    int r = tr + i * 8;
    ld[r][tc] = in[(size_t)(r0 + r) * C + c0 + tc];
  }
  __syncthreads();
#pragma unroll
  for (int i = 0; i < 4; ++i) {
    int r = tr + i * 8;
    out[(size_t)(c0 + r) * R + r0 + tc] = f2bf(ld[tc][r]);
  }
}

// ---------------- RoPE cos/sin tables: [S][64] each ----------------
__global__ void k_rope_tables(float* __restrict__ cost, float* __restrict__ sint) {
  int i = blockIdx.x * 256 + threadIdx.x;  // < S_*64
  int s = i >> 6, j = i & 63;
  double th = pow(10000.0, -(double)j / 64.0);
  double a = (double)s * th;
  cost[i] = (float)cos(a);
  sint[i] = (float)sin(a);
}

// ---------------- bf16 GEMM: C[M][N] = A[M][K] * Bt[N][K]^T (+bias) ----------------
template <int FINAL>
__global__ __launch_bounds__(256, 2) void k_gemm_bt(const ushort_t* __restrict__ A,
                                                    const ushort_t* __restrict__ Bt,
                                                    void* __restrict__ Cout,
                                                    const float* __restrict__ bias,
                                                    int M, int N, int K) {
  __shared__ __attribute__((aligned(16))) ushort_t As[128 * 32];
  __shared__ __attribute__((aligned(16))) ushort_t Bs[128 * 32];
  const int tid = threadIdx.x;
  const int w = tid >> 6, l = tid & 63;
  const int lr = l & 15, lg = l >> 4;
  const int m0 = blockIdx.y * 128, n0 = blockIdx.x * 128;
  const int wr = (w >> 1) * 64, wc = (w & 1) * 64;
  f32x4 acc[4][4] = {};
  for (int kt = 0; kt < K; kt += 32) {
#pragma unroll
    for (int i = 0; i < 2; ++i) {
      int c = i * 256 + w * 64 + l;  // 16B chunk id; row=c>>2, sub=c&3
      const ushort_t* ga = A + (size_t)(m0 + (c >> 2)) * K + kt + (c & 3) * 8;
      const ushort_t* gb = Bt + (size_t)(n0 + (c >> 2)) * K + kt + (c & 3) * 8;
      __builtin_amdgcn_global_load_lds(
          (const __attribute__((address_space(1))) u32*)ga,
          (__attribute__((address_space(3))) u32*)(As + (size_t)(i * 256 + w * 64) * 8), 16, 0, 0);
      __builtin_amdgcn_global_load_lds(
          (const __attribute__((address_space(1))) u32*)gb,
          (__attribute__((address_space(3))) u32*)(Bs + (size_t)(i * 256 + w * 64) * 8), 16, 0, 0);
    }
    __syncthreads();
    bf16x8 af[4], bfr[4];
#pragma unroll
    for (int m = 0; m < 4; ++m)
      af[m] = *(const bf16x8*)(As + (wr + m * 16 + lr) * 32 + lg * 8);
#pragma unroll
    for (int n = 0; n < 4; ++n)
      bfr[n] = *(const bf16x8*)(Bs + (wc + n * 16 + lr) * 32 + lg * 8);
#pragma unroll
    for (int m = 0; m < 4; ++m)
#pragma unroll
      for (int n = 0; n < 4; ++n)
        acc[m][n] = __builtin_amdgcn_mfma_f32_16x16x32_bf16(af[m], bfr[n], acc[m][n], 0, 0, 0);
    __syncthreads();
  }
#pragma unroll
  for (int m = 0; m < 4; ++m) {
#pragma unroll
    for (int n = 0; n < 4; ++n) {
#pragma unroll
      for (int j = 0; j < 4; ++j) {
        int row = m0 + wr + m * 16 + lg * 4 + j;
        int col = n0 + wc + n * 16 + lr;
        if (FINAL) {
          ((float*)Cout)[(size_t)row * N + col] = acc[m][n][j] + bias[col];
        } else {
          ((ushort_t*)Cout)[(size_t)row * N + col] = f2bf(acc[m][n][j]);
        }
      }
    }
  }
}

// ---------------- split QKV slice; RoPE for Q/K; transpose for V ----------------
__global__ void k_split_rope(const ushort_t* __restrict__ tmp, ushort_t* __restrict__ dst,
                             const float* __restrict__ cost, const float* __restrict__ sint,
                             int mode) {
  int s0 = blockIdx.x * 32;
  int h = blockIdx.y;
  int b = blockIdx.z;
  int bh = b * H_ + h;
  if (mode < 2) {
#pragma unroll
    for (int i = 0; i < 16; ++i) {
      int e = i * 256 + threadIdx.x;
      int sr = e >> 7, d = e & 127;
      int s = s0 + sr;
      size_t base = (size_t)(b * S_ + s) * D_ + h * HD_;
      float v = bf2f(tmp[base + d]);
      int j = d & 63;
      float cth = cost[s * 64 + j], sth = sint[s * 64 + j];
      int pd = (d < 64) ? d + 64 : d - 64;
      float v2 = bf2f(tmp[base + pd]);
      float r = (d < 64) ? v * cth - v2 * sth : v * cth + v2 * sth;
      dst[((size_t)bh * S_ + s) * HD_ + d] = f2bf(r);
    }
  } else {
    __shared__ ushort_t ld[32][132];
#pragma unroll
    for (int i = 0; i < 16; ++i) {
      int e = i * 256 + threadIdx.x;
      int sr = e >> 7, d = e & 127;
      ld[sr][d] = tmp[(size_t)(b * S_ + s0 + sr) * D_ + h * HD_ + d];
    }
    __syncthreads();
#pragma unroll
    for (int i = 0; i < 16; ++i) {
      int e = i * 256 + threadIdx.x;
      int d = e >> 5, sr = e & 31;
      dst[((size_t)bh * HD_ + d) * S_ + s0 + sr] = ld[sr][d];
    }
  }
}

// ---------------- causal flash attention v2 ----------------
// Q,K: [B*H][S][HD] bf16 (RoPE'd); Vt: [B*H][HD][S] bf16; O: [B][S][H*HD] bf16
// 4 waves/block, 32 q rows/wave (2 fragments), KVBLK=64 staged in swizzled LDS
// shared by all waves. Swapped QK^T: lane owns q = lane&15 of each fragment.
__global__ __launch_bounds__(256, 2) void k_attn2(const ushort_t* __restrict__ Q,
                                                  const ushort_t* __restrict__ K,
                                                  const ushort_t* __restrict__ Vt,
                                                  ushort_t* __restrict__ O) {
  __shared__ __attribute__((aligned(16))) ushort_t Ks[64 * 128];   // 16KB, XOR-swizzled rows
  __shared__ __attribute__((aligned(16))) ushort_t Vs[128 * 64];   // 16KB, XOR-swizzled rows
  __shared__ __attribute__((aligned(16))) ushort_t Pl[8][16 * 72]; // per wave x frag P buffer

  // block remap: XCD-chunked (id&7 -> contiguous bh range), longest-qt-first
  int id = blockIdx.x;                 // 0..1023
  int work = (id & 7) * 128 + (id >> 3);
  int bh = work >> 4;
  int qt = 15 - (work & 15);
  int b = bh >> 4, h = bh & 15;

  const int tid = threadIdx.x;
  const int w = tid >> 6, l = tid & 63;
  const int lr = l & 15, lg = l >> 4;
  const int qb = qt * 128 + w * 32;    // wave's first q row

  const ushort_t* Qp = Q + (size_t)bh * S_ * HD_;
  const char* Kpb = (const char*)(K + (size_t)bh * S_ * HD_);
  const char* Vpb = (const char*)(Vt + (size_t)bh * HD_ * S_);
  const float scale = 0.08838834764831845f;  // 1/sqrt(128)

  // staging address precompute (involutive XOR swizzle, rule #21: inverse-swz source)
  int krow[4], koff[4], vrow[4], voff[4];
#pragma unroll
  for (int r = 0; r < 4; ++r) {
    int c = r * 256 + tid;
    krow[r] = c >> 4;
    koff[r] = (((c & 15) ^ (krow[r] & 7)) << 4);
    vrow[r] = c >> 3;
    voff[r] = (((c & 7) ^ (vrow[r] & 7)) << 4);
  }
  const int swz = (lr & 7) << 4;  // read-side swizzle (row & 7 == lr & 7 for our rows)

  // Q fragments: 2 x 4 (32 q rows per wave)
  bf16x8 qf[2][4];
#pragma unroll
  for (int f = 0; f < 2; ++f)
#pragma unroll
    for (int dw = 0; dw < 4; ++dw)
      qf[f][dw] = *(const bf16x8*)(Qp + (size_t)(qb + f * 16 + lr) * HD_ + dw * 32 + lg * 8);

  f32x4 oacc[2][8] = {};
  float mr[2] = {-1e30f, -1e30f};
  float lsum[2] = {0.f, 0.f};
  const int nkt = 2 * qt + 2;

  for (int kt = 0; kt < nkt; ++kt) {
    const int kb = kt * 64;
    // ---- stage K (64x128) and V (128x64) tiles, all waves ----
#pragma unroll
    for (int r = 0; r < 4; ++r) {
      __builtin_amdgcn_global_load_lds(
          (const __attribute__((address_space(1))) u32*)(Kpb + (size_t)(kb + krow[r]) * 256 + koff[r]),
          (__attribute__((address_space(3))) u32*)(Ks + (r * 256 + w * 64) * 8), 16, 0, 0);
    }
#pragma unroll
    for (int r = 0; r < 4; ++r) {
      __builtin_amdgcn_global_load_lds(
          (const __attribute__((address_space(1))) u32*)(Vpb + (size_t)vrow[r] * (S_ * 2) + kb * 2 + voff[r]),
          (__attribute__((address_space(3))) u32*)(Vs + (r * 256 + w * 64) * 8), 16, 0, 0);
    }
    __syncthreads();

    if (kb <= qb + 31) {  // wave has live rows in this k tile
      // ---- QK^T (swapped): st[f] scores for q = qb + f*16 + lr ----
      f32x4 st[2][4];
      __builtin_amdgcn_s_setprio(1);
#pragma unroll
      for (int t = 0; t < 4; ++t) {
        bf16x8 kf[4];
#pragma unroll
        for (int dw = 0; dw < 4; ++dw)
          kf[dw] = *(const bf16x8*)((const char*)Ks + (t * 16 + lr) * 256 + ((dw * 64 + lg * 16) ^ swz));
        f32x4 a0 = {}, a1 = {};
#pragma unroll
        for (int dw = 0; dw < 4; ++dw) {
          a0 = __builtin_amdgcn_mfma_f32_16x16x32_bf16(kf[dw], qf[0][dw], a0, 0, 0, 0);
          a1 = __builtin_amdgcn_mfma_f32_16x16x32_bf16(kf[dw], qf[1][dw], a1, 0, 0, 0);
        }
        st[0][t] = a0;
        st[1][t] = a1;
      }
      __builtin_amdgcn_s_setprio(0);

      // ---- online softmax per fragment ----
#pragma unroll
      for (int f = 0; f < 2; ++f) {
        const int qg = qb + f * 16 + lr;
        float tmax = -1e30f;
#pragma unroll
        for (int t = 0; t < 4; ++t) {
#pragma unroll
          for (int j = 0; j < 4; ++j) {
            int kg = kb + t * 16 + lg * 4 + j;
            float s = st[f][t][j] * scale;
            s = (kg > qg) ? -1e30f : s;
            st[f][t][j] = s;
            tmax = fmaxf(tmax, s);
          }
        }
        tmax = fmaxf(tmax, __shfl_xor(tmax, 16, 64));
        tmax = fmaxf(tmax, __shfl_xor(tmax, 32, 64));
        float mnew = fmaxf(mr[f], tmax);
        float alpha = __expf(mr[f] - mnew);
        mr[f] = mnew;
        float psum = 0.f;
        ushort_t* Pw = Pl[w * 2 + f];
#pragma unroll
        for (int t = 0; t < 4; ++t) {
          float p0 = __expf(st[f][t][0] - mnew);
          float p1 = __expf(st[f][t][1] - mnew);
          float p2 = __expf(st[f][t][2] - mnew);
          float p3 = __expf(st[f][t][3] - mnew);
          psum += (p0 + p1) + (p2 + p3);
          *(u32*)&Pw[lr * 72 + t * 16 + lg * 4] = (u32)f2bf(p0) | ((u32)f2bf(p1) << 16);
          *(u32*)&Pw[lr * 72 + t * 16 + lg * 4 + 2] = (u32)f2bf(p2) | ((u32)f2bf(p3) << 16);
        }
        psum += __shfl_xor(psum, 16, 64);
        psum += __shfl_xor(psum, 32, 64);
        lsum[f] = lsum[f] * alpha + psum;
        float a0 = __shfl(alpha, lg * 4 + 0, 64);
        float a1 = __shfl(alpha, lg * 4 + 1, 64);
        float a2 = __shfl(alpha, lg * 4 + 2, 64);
        float a3 = __shfl(alpha, lg * 4 + 3, 64);
#pragma unroll
        for (int dt = 0; dt < 8; ++dt) {
          oacc[f][dt][0] *= a0;
          oacc[f][dt][1] *= a1;
          oacc[f][dt][2] *= a2;
          oacc[f][dt][3] *= a3;
        }
      }

      // ---- PV: A = P[16q x 32k] (LDS), B = Vs[k][d] slices; V reads shared by frags ----
      __builtin_amdgcn_s_setprio(1);
#pragma unroll
      for (int kw = 0; kw < 2; ++kw) {
        bf16x8 pa0 = *(const bf16x8*)&Pl[w * 2 + 0][lr * 72 + kw * 32 + lg * 8];
        bf16x8 pa1 = *(const bf16x8*)&Pl[w * 2 + 1][lr * 72 + kw * 32 + lg * 8];
#pragma unroll
        for (int dt = 0; dt < 8; ++dt) {
          bf16x8 vf = *(const bf16x8*)((const char*)Vs + (dt * 16 + lr) * 128 + ((kw * 64 + lg * 16) ^ swz));
          oacc[0][dt] = __builtin_amdgcn_mfma_f32_16x16x32_bf16(pa0, vf, oacc[0][dt], 0, 0, 0);
          oacc[1][dt] = __builtin_amdgcn_mfma_f32_16x16x32_bf16(pa1, vf, oacc[1][dt], 0, 0, 0);
        }
      }
      __builtin_amdgcn_s_setprio(0);
    }
    __syncthreads();
  }

  // ---- epilogue ----
#pragma unroll
  for (int f = 0; f < 2; ++f) {
    float l0 = __shfl(lsum[f], lg * 4 + 0, 64);
    float l1 = __shfl(lsum[f], lg * 4 + 1, 64);
    float l2 = __shfl(lsum[f], lg * 4 + 2, 64);
    float l3 = __shfl(lsum[f], lg * 4 + 3, 64);
    float i0 = 1.f / l0, i1 = 1.f / l1, i2 = 1.f / l2, i3 = 1.f / l3;
    ushort_t* Op = O + (size_t)(b * S_ + qb + f * 16) * D_ + h * HD_;
#pragma unroll
    for (int dt = 0; dt < 8; ++dt) {
      Op[(size_t)(lg * 4 + 0) * D_ + dt * 16 + lr] = f2bf(oacc[f][dt][0] * i0);
      Op[(size_t)(lg * 4 + 1) * D_ + dt * 16 + lr] = f2bf(oacc[f][dt][1] * i1);
      Op[(size_t)(lg * 4 + 2) * D_ + dt * 16 + lr] = f2bf(oacc[f][dt][2] * i2);
      Op[(size_t)(lg * 4 + 3) * D_ + dt * 16 + lr] = f2bf(oacc[f][dt][3] * i3);
    }
  }
}

// ---------------- launch ----------------
extern "C" void kernel_launch(void* const* d_in, const int* in_sizes, int n_in,
                              void* d_out, int out_size, void* d_ws, size_t ws_size,
                              hipStream_t stream) {
  const float* x = (const float*)d_in[0];
  const float* Wqkv = (const float*)d_in[1];
  const float* Wout = (const float*)d_in[2];
  const float* bout = (const float*)d_in[3];
  char* ws = (char*)d_ws;

  ushort_t* xb = (ushort_t*)(ws + 0);                  // [8192][2048] bf16 -> later O
  ushort_t* Wqt = (ushort_t*)(ws + 33554432ull);       // [6144][2048] bf16
  ushort_t* tmp = (ushort_t*)(ws + 58720256ull);       // [8192][2048] bf16 -> later Wout^T
  ushort_t* Qb = (ushort_t*)(ws + 92274688ull);        // [64][2048][128]
  ushort_t* Kb = (ushort_t*)(ws + 125829120ull);       // [64][2048][128]
  ushort_t* Vb = (ushort_t*)(ws + 159383552ull);       // [64][128][2048]
  float* cost = (float*)(ws + 192937984ull);           // [2048][64]
  float* sint = (float*)(ws + 193462272ull);           // [2048][64]

  const int M = B_ * S_;  // 8192

  k_cvt_bf16<<<dim3((M * D_) / 4 / 256), 256, 0, stream>>>(x, xb, M * D_);
  k_transpose_bf16<<<dim3(3 * D_ / 32, D_ / 32), 256, 0, stream>>>(Wqkv, Wqt, D_, 3 * D_);
  k_rope_tables<<<dim3(S_ * 64 / 256), 256, 0, stream>>>(cost, sint);

  for (int p = 0; p < 3; ++p) {
    k_gemm_bt<0><<<dim3(D_ / 128, M / 128), 256, 0, stream>>>(
        xb, Wqt + (size_t)p * D_ * D_, tmp, nullptr, M, D_, D_);
    ushort_t* dst = (p == 0) ? Qb : (p == 1) ? Kb : Vb;
    k_split_rope<<<dim3(S_ / 32, H_, B_), 256, 0, stream>>>(tmp, dst, cost, sint, p);
  }

  k_attn2<<<dim3((S_ / 128) * B_ * H_), 256, 0, stream>>>(Qb, Kb, Vb, xb /* reuse as O */);

  k_transpose_bf16<<<dim3(D_ / 32, D_ / 32), 256, 0, stream>>>(Wout, tmp, D_, D_);
  k_gemm_bt<1><<<dim3(D_ / 128, M / 128), 256, 0, stream>>>(
      xb, tmp, d_out, bout, M, D_, D_);
}